// Round 17
// baseline (126.038 us; speedup 1.0000x reference)
//
#include <hip/hip_runtime.h>
#include <math.h>

#define NHEAD 8
#define CEMB  256
#define NIN   2
#define BB    4
#define TT    8192
#define SLOTS 128

typedef __attribute__((ext_vector_type(8))) short short8;
typedef __attribute__((ext_vector_type(4))) float f32x4;
typedef __attribute__((ext_vector_type(16))) float f32x16;

__device__ __forceinline__ unsigned short f2bf(float f) {
    union { float f; unsigned u; } v; v.f = f;
    unsigned u = v.u;
    return (unsigned short)((u + 0x7fffu + ((u >> 16) & 1u)) >> 16);
}
__device__ __forceinline__ float bf2f(unsigned short s) {
    union { unsigned u; float f; } v; v.u = ((unsigned)s) << 16;
    return v.f;
}

// ---- prep: convert + transpose all weights to bf16: Wt[n][k] = W[k][n] ----
__global__ __launch_bounds__(256) void prep_w(const float* __restrict__ Wq,
    const float* __restrict__ Wk, const float* __restrict__ Wv,
    const float* __restrict__ Wp, unsigned short* __restrict__ wsb)
{
    int gid = blockIdx.x * 256 + threadIdx.x;   // 6*65536
    int m = gid >> 16;
    int idx = gid & 65535;
    int n = idx >> 8, k = idx & 255;
    const float* src; unsigned short* dst;
    switch (m) {
        case 0: src = Wq;          dst = wsb;          break;
        case 1: src = Wk;          dst = wsb + 65536;  break;
        case 2: src = Wk + 65536;  dst = wsb + 131072; break;
        case 3: src = Wv;          dst = wsb + 196608; break;
        case 4: src = Wv + 65536;  dst = wsb + 262144; break;
        default: src = Wp;         dst = wsb + 327680; break;
    }
    dst[n * 256 + k] = f2bf(src[k * 256 + n]);
}

// ---- pass A: 512 thr / 8 waves, wave w owns head w; 32-row tiles x ITERS=2;
//      LDS 34.4KB -> 3-4 blocks/CU; (512,2) safe bound; bf16 partials ----
__global__ __launch_bounds__(512, 2) void passA(const float* __restrict__ y,
    const float* __restrict__ bk, const float* __restrict__ bv,
    const unsigned short* __restrict__ Wkt, const unsigned short* __restrict__ Wvt,
    unsigned short* __restrict__ part)
{
    __shared__ unsigned short ytile[32][256];   // XOR-swizzled 16B units (16KB)
    __shared__ unsigned short tr[8][32][36];    // per-wave transpose buf, pad-36 (18.4KB)

    const int i = blockIdx.z, b = blockIdx.y, x0 = blockIdx.x;
    const int tid = threadIdx.x;
    const int wid = tid >> 6, lane = tid & 63;
    const int lg = lane >> 4, li = lane & 15;
    const int l31 = lane & 31, hk = lane >> 5;
    const int h = wid, lm = li & 7;

    const float bk0 = bk[i * CEMB + h * 32 + li];
    const float bk1 = bk[i * CEMB + h * 32 + 16 + li];
    const float bv0 = bv[i * CEMB + h * 32 + li];
    const float bv1 = bv[i * CEMB + h * 32 + 16 + li];

    const unsigned short* wk0 = Wkt + ((size_t)(i * 256 + h * 32 + li)) * 256 + lg * 8;
    const unsigned short* wk1 = wk0 + 16 * 256;
    const unsigned short* wv0 = Wvt + ((size_t)(i * 256 + h * 32 + li)) * 256 + lg * 8;
    const unsigned short* wv1 = wv0 + 16 * 256;

    f32x16 kvacc = {};
    float ksa0 = 0.f, ksa1 = 0.f;

    #pragma unroll
    for (int iter = 0; iter < 2; ++iter) {
        __syncthreads();
        const int row0 = x0 * 64 + iter * 32;
        const float* yb = y + ((size_t)(i * BB + b) * TT + row0) * CEMB;
        #pragma unroll
        for (int j = 0; j < 4; ++j) {
            int idx = tid + j * 512;
            int r = idx >> 6, c4 = (idx & 63) << 2;
            int sw = ((((c4 >> 3) ^ (r & 7)) << 3) | (c4 & 7));
            float4 v4 = *(const float4*)&yb[(size_t)r * CEMB + c4];
            ushort4 p; p.x = f2bf(v4.x); p.y = f2bf(v4.y); p.z = f2bf(v4.z); p.w = f2bf(v4.w);
            *(ushort4*)&ytile[r][sw] = p;
        }
        __syncthreads();

        // ---------- K GEMM: acc[2][2] over 32 rows ----------
        f32x4 acc00 = {}, acc01 = {}, acc10 = {}, acc11 = {};
        #pragma unroll 2
        for (int ks = 0; ks < 8; ++ks) {
            const int sw8 = (((4 * ks + lg) ^ lm) << 3);
            short8 a0 = *(const short8*)&ytile[li][sw8];
            short8 a1 = *(const short8*)&ytile[16 + li][sw8];
            short8 f0 = *(const short8*)(wk0 + ks * 32);
            short8 f1 = *(const short8*)(wk1 + ks * 32);
            acc00 = __builtin_amdgcn_mfma_f32_16x16x32_bf16(a0, f0, acc00, 0, 0, 0);
            acc01 = __builtin_amdgcn_mfma_f32_16x16x32_bf16(a0, f1, acc01, 0, 0, 0);
            acc10 = __builtin_amdgcn_mfma_f32_16x16x32_bf16(a1, f0, acc10, 0, 0, 0);
            acc11 = __builtin_amdgcn_mfma_f32_16x16x32_bf16(a1, f1, acc11, 0, 0, 0);
        }
        // softmax(k) without max-sub -> kT into tr[wid] ([d=32][t=32], pad-36)
        #pragma unroll
        for (int rt = 0; rt < 2; ++rt) {
            f32x4 A0 = rt ? acc10 : acc00;
            f32x4 A1 = rt ? acc11 : acc01;
            float kq0[4], kq1[4];
            #pragma unroll
            for (int reg = 0; reg < 4; ++reg) {
                float e0 = __expf(A0[reg] + bk0);
                float e1 = __expf(A1[reg] + bk1);
                float s = e0 + e1;
                s += __shfl_xor(s, 1, 16);
                s += __shfl_xor(s, 2, 16);
                s += __shfl_xor(s, 4, 16);
                s += __shfl_xor(s, 8, 16);
                float isv = 1.f / s;
                kq0[reg] = e0 * isv; kq1[reg] = e1 * isv;
                ksa0 += kq0[reg]; ksa1 += kq1[reg];
            }
            ushort4 p;
            p.x = f2bf(kq0[0]); p.y = f2bf(kq0[1]); p.z = f2bf(kq0[2]); p.w = f2bf(kq0[3]);
            *(ushort4*)&tr[wid][li][16 * rt + 4 * lg] = p;
            p.x = f2bf(kq1[0]); p.y = f2bf(kq1[1]); p.z = f2bf(kq1[2]); p.w = f2bf(kq1[3]);
            *(ushort4*)&tr[wid][16 + li][16 * rt + 4 * lg] = p;
        }
        // ---------- V GEMM: reuse acc ----------
        acc00 = (f32x4){}; acc01 = (f32x4){}; acc10 = (f32x4){}; acc11 = (f32x4){};
        #pragma unroll 2
        for (int ks = 0; ks < 8; ++ks) {
            const int sw8 = (((4 * ks + lg) ^ lm) << 3);
            short8 a0 = *(const short8*)&ytile[li][sw8];
            short8 a1 = *(const short8*)&ytile[16 + li][sw8];
            short8 f0 = *(const short8*)(wv0 + ks * 32);
            short8 f1 = *(const short8*)(wv1 + ks * 32);
            acc00 = __builtin_amdgcn_mfma_f32_16x16x32_bf16(a0, f0, acc00, 0, 0, 0);
            acc01 = __builtin_amdgcn_mfma_f32_16x16x32_bf16(a0, f1, acc01, 0, 0, 0);
            acc10 = __builtin_amdgcn_mfma_f32_16x16x32_bf16(a1, f0, acc10, 0, 0, 0);
            acc11 = __builtin_amdgcn_mfma_f32_16x16x32_bf16(a1, f1, acc11, 0, 0, 0);
        }
        // read K fragments before overwriting tr with V (wave-private buf)
        asm volatile("s_waitcnt lgkmcnt(0)" ::: "memory");
        short8 ka0 = *(const short8*)&tr[wid][l31][hk * 8];
        short8 ka1 = *(const short8*)&tr[wid][l31][16 + hk * 8];
        asm volatile("s_waitcnt lgkmcnt(0)" ::: "memory");
        // vT into tr
        #pragma unroll
        for (int rt = 0; rt < 2; ++rt) {
            f32x4 A0 = rt ? acc10 : acc00;
            f32x4 A1 = rt ? acc11 : acc01;
            ushort4 p;
            p.x = f2bf(A0[0] + bv0); p.y = f2bf(A0[1] + bv0);
            p.z = f2bf(A0[2] + bv0); p.w = f2bf(A0[3] + bv0);
            *(ushort4*)&tr[wid][li][16 * rt + 4 * lg] = p;
            p.x = f2bf(A1[0] + bv1); p.y = f2bf(A1[1] + bv1);
            p.z = f2bf(A1[2] + bv1); p.w = f2bf(A1[3] + bv1);
            *(ushort4*)&tr[wid][16 + li][16 * rt + 4 * lg] = p;
        }
        asm volatile("s_waitcnt lgkmcnt(0)" ::: "memory");
        {
            short8 vb0 = *(const short8*)&tr[wid][l31][hk * 8];
            short8 vb1 = *(const short8*)&tr[wid][l31][16 + hk * 8];
            kvacc = __builtin_amdgcn_mfma_f32_32x32x16_bf16(ka0, vb0, kvacc, 0, 0, 0);
            kvacc = __builtin_amdgcn_mfma_f32_32x32x16_bf16(ka1, vb1, kvacc, 0, 0, 0);
        }
        asm volatile("s_waitcnt lgkmcnt(0)" ::: "memory");
    }

    const size_t slot = (size_t)(i * BB + b) * SLOTS + x0;
    unsigned short* pb = part + slot * (NHEAD * 1056) + (size_t)h * 1056;
    #pragma unroll
    for (int reg = 0; reg < 16; ++reg) {
        int d = (reg & 3) + 8 * (reg >> 2) + 4 * hk;
        pb[d * 32 + l31] = f2bf(kvacc[reg]);
    }
    float s0 = ksa0, s1 = ksa1;
    s0 += __shfl_xor(s0, 16, 64); s0 += __shfl_xor(s0, 32, 64);
    s1 += __shfl_xor(s1, 16, 64); s1 += __shfl_xor(s1, 32, 64);
    if (lg == 0) { pb[1024 + li] = f2bf(s0); pb[1024 + 16 + li] = f2bf(s1); }
}

// ---- reduce bf16 partials (single stage, SLOTS summands, f32 accum) ----
__global__ __launch_bounds__(256) void reduceKV(const unsigned short* __restrict__ part,
    unsigned short* __restrict__ kvt, float* __restrict__ ksum)
{
    const int g = blockIdx.y, ech = blockIdx.x;
    const int ib = g >> 3, h = g & 7;
    const int tid = threadIdx.x;
    const int e0 = ech * 264;
    const int e1 = (e0 + 264 < 1056) ? e0 + 264 : 1056;
    for (int e = e0 + tid; e < e1; e += 256) {
        float s = 0.f;
        const unsigned short* p = part + ((size_t)ib * SLOTS * NHEAD + h) * 1056 + e;
        #pragma unroll 8
        for (int xx = 0; xx < SLOTS; ++xx) s += bf2f(p[(size_t)xx * NHEAD * 1056]);
        if (e < 1024) kvt[(size_t)g * 1024 + (e & 31) * 32 + (e >> 5)] = f2bf(s);
        else          ksum[(size_t)g * 32 + (e - 1024)] = s;
    }
}

// ---- pass B (R6 structure; max-drop softmax): 512 thr, wave w owns head w ----
__global__ __launch_bounds__(512, 4) void passB(const float* __restrict__ x,
    const float* __restrict__ bq, const float* __restrict__ bp,
    const unsigned short* __restrict__ Wqt, const unsigned short* __restrict__ Wpt,
    const unsigned short* __restrict__ kvt, const float* __restrict__ ksum,
    float* __restrict__ out)
{
    __shared__ unsigned short xa[64][256];     // XOR-swizzled; reused as out_pre
    __shared__ unsigned short ql[64][256];     // XOR-swizzled
    __shared__ float dl[2][64][8];

    const int b = blockIdx.y, x0 = blockIdx.x;
    const int row0 = x0 * 64;
    const int tid = threadIdx.x;
    const int wid = tid >> 6, lane = tid & 63, lg = lane >> 4, li = lane & 15;
    const int h = wid, lm = li & 7;

    const float* xb = x + ((size_t)b * TT + row0) * CEMB;
    #pragma unroll
    for (int j = 0; j < 8; ++j) {
        int idx = tid + j * 512;
        int r = idx >> 6, c4 = (idx & 63) << 2;
        int sw = ((((c4 >> 3) ^ (r & 7)) << 3) | (c4 & 7));
        float4 v4 = *(const float4*)&xb[(size_t)r * CEMB + c4];
        ushort4 p; p.x = f2bf(v4.x); p.y = f2bf(v4.y); p.z = f2bf(v4.z); p.w = f2bf(v4.w);
        *(ushort4*)&xa[r][sw] = p;
    }
    __syncthreads();

    // q projection: wave owns head h (2 col-tiles of 16)
    {
        f32x4 qa[4][2];
        #pragma unroll
        for (int rt = 0; rt < 4; ++rt) { qa[rt][0] = (f32x4){}; qa[rt][1] = (f32x4){}; }

        const unsigned short* wq0 = Wqt + ((size_t)(h * 32 + li)) * 256 + lg * 8;
        const unsigned short* wq1 = wq0 + 16 * 256;
        #pragma unroll 2
        for (int ks = 0; ks < 8; ++ks) {
            const int sw8 = (((4 * ks + lg) ^ lm) << 3);
            short8 a0 = *(const short8*)&xa[li][sw8];
            short8 a1 = *(const short8*)&xa[16 + li][sw8];
            short8 a2 = *(const short8*)&xa[32 + li][sw8];
            short8 a3 = *(const short8*)&xa[48 + li][sw8];
            short8 f0 = *(const short8*)(wq0 + ks * 32);
            short8 f1 = *(const short8*)(wq1 + ks * 32);
            qa[0][0] = __builtin_amdgcn_mfma_f32_16x16x32_bf16(a0, f0, qa[0][0], 0, 0, 0);
            qa[0][1] = __builtin_amdgcn_mfma_f32_16x16x32_bf16(a0, f1, qa[0][1], 0, 0, 0);
            qa[1][0] = __builtin_amdgcn_mfma_f32_16x16x32_bf16(a1, f0, qa[1][0], 0, 0, 0);
            qa[1][1] = __builtin_amdgcn_mfma_f32_16x16x32_bf16(a1, f1, qa[1][1], 0, 0, 0);
            qa[2][0] = __builtin_amdgcn_mfma_f32_16x16x32_bf16(a2, f0, qa[2][0], 0, 0, 0);
            qa[2][1] = __builtin_amdgcn_mfma_f32_16x16x32_bf16(a2, f1, qa[2][1], 0, 0, 0);
            qa[3][0] = __builtin_amdgcn_mfma_f32_16x16x32_bf16(a3, f0, qa[3][0], 0, 0, 0);
            qa[3][1] = __builtin_amdgcn_mfma_f32_16x16x32_bf16(a3, f1, qa[3][1], 0, 0, 0);
        }
        const float bq0 = bq[h * 32 + li];
        const float bq1 = bq[h * 32 + 16 + li];
        #pragma unroll
        for (int rt = 0; rt < 4; ++rt) {
            #pragma unroll
            for (int reg = 0; reg < 4; ++reg) {
                float e0 = __expf(qa[rt][0][reg] + bq0);
                float e1 = __expf(qa[rt][1][reg] + bq1);
                float s = e0 + e1;
                s += __shfl_xor(s, 1, 16);
                s += __shfl_xor(s, 2, 16);
                s += __shfl_xor(s, 4, 16);
                s += __shfl_xor(s, 8, 16);
                float isv = 1.f / s;
                int r = 16 * rt + 4 * lg + reg;
                int r7 = r & 7;
                int sw0 = (((4 * h + (li >> 3)) ^ r7) << 3) | lm;
                int sw1 = (((4 * h + 2 + (li >> 3)) ^ r7) << 3) | lm;
                ql[r][sw0] = f2bf(e0 * isv);
                ql[r][sw1] = f2bf(e1 * isv);
            }
        }
    }
    __syncthreads();

    // Dinv: 512 threads cover 64 rows x 8 heads
    {
        int r = tid >> 3, hh = tid & 7;
        const float* ks0 = ksum + ((size_t)(0 * BB + b) * 8 + hh) * 32;
        const float* ks1 = ksum + ((size_t)(1 * BB + b) * 8 + hh) * 32;
        float s0 = 0.f, s1 = 0.f;
        #pragma unroll
        for (int d8 = 0; d8 < 4; ++d8) {
            int cu = (((4 * hh + d8) ^ (r & 7)) << 3);
            #pragma unroll
            for (int dd = 0; dd < 8; ++dd) {
                float qv = bf2f(ql[r][cu + dd]);
                s0 += qv * ks0[d8 * 8 + dd];
                s1 += qv * ks1[d8 * 8 + dd];
            }
        }
        dl[0][r][hh] = 1.f / s0;
        dl[1][r][hh] = 1.f / s1;
    }
    __syncthreads();

    // attn for own head h: out_pre cols [h*32, h*32+32) over all 64 rows -> xa
    #pragma unroll
    for (int rt = 0; rt < 4; ++rt) {
        float of0[4], of1[4];
        #pragma unroll
        for (int reg = 0; reg < 4; ++reg) {
            int rk = (4 * lg + reg) & 7;
            int r = 16 * rt + 4 * lg + reg;
            int col0 = (((4 * h + (li >> 3)) ^ rk) << 3) | lm;
            int col1 = (((4 * h + 2 + (li >> 3)) ^ rk) << 3) | lm;
            of0[reg] = bf2f(ql[r][col0]);
            of1[reg] = bf2f(ql[r][col1]);
        }
        short8 af = *(const short8*)&ql[16 * rt + li][(((4 * h + lg) ^ lm) << 3)];
        #pragma unroll
        for (int ii = 0; ii < NIN; ++ii) {
            const unsigned short* kvb = kvt + ((size_t)((ii * BB + b) * 8 + h)) * 1024;
            short8 b0 = *(const short8*)(kvb + (size_t)li * 32 + lg * 8);
            short8 b1 = *(const short8*)(kvb + (size_t)(16 + li) * 32 + lg * 8);
            f32x4 z = {};
            f32x4 t0 = __builtin_amdgcn_mfma_f32_16x16x32_bf16(af, b0, z, 0, 0, 0);
            f32x4 t1 = __builtin_amdgcn_mfma_f32_16x16x32_bf16(af, b1, z, 0, 0, 0);
            #pragma unroll
            for (int reg = 0; reg < 4; ++reg) {
                float dv = dl[ii][16 * rt + 4 * lg + reg][h];
                of0[reg] += t0[reg] * dv;
                of1[reg] += t1[reg] * dv;
            }
        }
        #pragma unroll
        for (int reg = 0; reg < 4; ++reg) {
            int rk = (4 * lg + reg) & 7;
            int r = 16 * rt + 4 * lg + reg;
            int col0 = (((4 * h + (li >> 3)) ^ rk) << 3) | lm;
            int col1 = (((4 * h + 2 + (li >> 3)) ^ rk) << 3) | lm;
            xa[r][col0] = f2bf(of0[reg]);
            xa[r][col1] = f2bf(of1[reg]);
        }
    }
    __syncthreads();   // cross-wave: out-proj reads all cols of xa

    // out projection: wave owns col-tiles 2h, 2h+1
    {
        f32x4 of[4][2];
        #pragma unroll
        for (int rt = 0; rt < 4; ++rt) { of[rt][0] = (f32x4){}; of[rt][1] = (f32x4){}; }
        const unsigned short* wp0 = Wpt + ((size_t)(h * 32 + li)) * 256 + lg * 8;
        const unsigned short* wp1 = wp0 + 16 * 256;
        #pragma unroll 2
        for (int ks = 0; ks < 8; ++ks) {
            const int sw8 = (((4 * ks + lg) ^ lm) << 3);
            short8 a0 = *(const short8*)&xa[li][sw8];
            short8 a1 = *(const short8*)&xa[16 + li][sw8];
            short8 a2 = *(const short8*)&xa[32 + li][sw8];
            short8 a3 = *(const short8*)&xa[48 + li][sw8];
            short8 f0 = *(const short8*)(wp0 + ks * 32);
            short8 f1 = *(const short8*)(wp1 + ks * 32);
            of[0][0] = __builtin_amdgcn_mfma_f32_16x16x32_bf16(a0, f0, of[0][0], 0, 0, 0);
            of[0][1] = __builtin_amdgcn_mfma_f32_16x16x32_bf16(a0, f1, of[0][1], 0, 0, 0);
            of[1][0] = __builtin_amdgcn_mfma_f32_16x16x32_bf16(a1, f0, of[1][0], 0, 0, 0);
            of[1][1] = __builtin_amdgcn_mfma_f32_16x16x32_bf16(a1, f1, of[1][1], 0, 0, 0);
            of[2][0] = __builtin_amdgcn_mfma_f32_16x16x32_bf16(a2, f0, of[2][0], 0, 0, 0);
            of[2][1] = __builtin_amdgcn_mfma_f32_16x16x32_bf16(a2, f1, of[2][1], 0, 0, 0);
            of[3][0] = __builtin_amdgcn_mfma_f32_16x16x32_bf16(a3, f0, of[3][0], 0, 0, 0);
            of[3][1] = __builtin_amdgcn_mfma_f32_16x16x32_bf16(a3, f1, of[3][1], 0, 0, 0);
        }
        const float bp0 = bp[h * 32 + li];
        const float bp1 = bp[h * 32 + 16 + li];
        #pragma unroll
        for (int rt = 0; rt < 4; ++rt) {
            #pragma unroll
            for (int reg = 0; reg < 4; ++reg) {
                int r = 16 * rt + 4 * lg + reg;
                float* ob = out + ((size_t)b * TT + row0 + r) * CEMB + h * 32;
                ob[li]      = of[rt][0][reg] + bp0;
                ob[16 + li] = of[rt][1][reg] + bp1;
            }
        }
    }
}

extern "C" void kernel_launch(void* const* d_in, const int* in_sizes, int n_in,
                              void* d_out, int out_size, void* d_ws, size_t ws_size,
                              hipStream_t stream)
{
    const float* x  = (const float*)d_in[0];
    const float* y  = (const float*)d_in[1];
    const float* Wq = (const float*)d_in[2];
    const float* bq = (const float*)d_in[3];
    const float* Wk = (const float*)d_in[4];
    const float* bk = (const float*)d_in[5];
    const float* Wv = (const float*)d_in[6];
    const float* bv = (const float*)d_in[7];
    const float* Wp = (const float*)d_in[8];
    const float* bp = (const float*)d_in[9];
    float* out = (float*)d_out;

    unsigned short* wsb = (unsigned short*)d_ws;
    // layout: weights 768KB | part (bf16) 2*4*128*8*1056*2 = 17.3MB | kvt 128KB | ksum 8KB
    unsigned short* part = (unsigned short*)((char*)d_ws + 786432);
    const size_t partBytes = (size_t)NIN * BB * SLOTS * NHEAD * 1056 * 2;
    unsigned short* kvt = (unsigned short*)((char*)d_ws + 786432 + partBytes);
    float* ksum = (float*)((char*)d_ws + 786432 + partBytes + 131072);

    hipLaunchKernelGGL(prep_w, dim3(1536), dim3(256), 0, stream, Wq, Wk, Wv, Wp, wsb);
    hipLaunchKernelGGL(passA, dim3(SLOTS, BB, NIN), dim3(512), 0, stream,
                       y, bk, bv, wsb + 65536, wsb + 196608, part);
    hipLaunchKernelGGL(reduceKV, dim3(4, 64), dim3(256), 0, stream, part, kvt, ksum);
    hipLaunchKernelGGL(passB, dim3(128, BB), dim3(512), 0, stream,
                       x, bq, bp, wsb + 0, wsb + 327680, kvt, ksum, out);
}

// Round 18
// 101.358 us; speedup vs baseline: 1.2435x; 1.2435x over previous
//
#include <hip/hip_runtime.h>
#include <math.h>

#define NHEAD 8
#define CEMB  256
#define NIN   2
#define BB    4
#define TT    8192
#define SLOTS 128

typedef __attribute__((ext_vector_type(8))) short short8;
typedef __attribute__((ext_vector_type(4))) float f32x4;
typedef __attribute__((ext_vector_type(16))) float f32x16;

__device__ __forceinline__ unsigned short f2bf(float f) {
    union { float f; unsigned u; } v; v.f = f;
    unsigned u = v.u;
    return (unsigned short)((u + 0x7fffu + ((u >> 16) & 1u)) >> 16);
}
__device__ __forceinline__ float bf2f(unsigned short s) {
    union { unsigned u; float f; } v; v.u = ((unsigned)s) << 16;
    return v.f;
}

// ---- prep: convert + transpose all weights to bf16: Wt[n][k] = W[k][n] ----
__global__ __launch_bounds__(256) void prep_w(const float* __restrict__ Wq,
    const float* __restrict__ Wk, const float* __restrict__ Wv,
    const float* __restrict__ Wp, unsigned short* __restrict__ wsb)
{
    int gid = blockIdx.x * 256 + threadIdx.x;   // 6*65536
    int m = gid >> 16;
    int idx = gid & 65535;
    int n = idx >> 8, k = idx & 255;
    const float* src; unsigned short* dst;
    switch (m) {
        case 0: src = Wq;          dst = wsb;          break;
        case 1: src = Wk;          dst = wsb + 65536;  break;
        case 2: src = Wk + 65536;  dst = wsb + 131072; break;
        case 3: src = Wv;          dst = wsb + 196608; break;
        case 4: src = Wv + 65536;  dst = wsb + 262144; break;
        default: src = Wp;         dst = wsb + 327680; break;
    }
    dst[n * 256 + k] = f2bf(src[k * 256 + n]);
}

// ---- pass A (R16 body + depth-1 weight-load pipeline): 512 thr, wave w owns head w ----
__global__ __launch_bounds__(512, 2) void passA(const float* __restrict__ y,
    const float* __restrict__ bk, const float* __restrict__ bv,
    const unsigned short* __restrict__ Wkt, const unsigned short* __restrict__ Wvt,
    unsigned short* __restrict__ part)
{
    __shared__ unsigned short ytile[64][256];   // XOR-swizzled 16B units (32KB)
    __shared__ unsigned short tr[8][32][68];    // per-wave transpose buf, pad-68 (34KB)

    const int i = blockIdx.z, b = blockIdx.y, x0 = blockIdx.x;
    const int tid = threadIdx.x;
    const int wid = tid >> 6, lane = tid & 63;
    const int lg = lane >> 4, li = lane & 15;
    const int l31 = lane & 31, hk = lane >> 5;
    const int h = wid, lm = li & 7;

    const float bk0 = bk[i * CEMB + h * 32 + li];
    const float bk1 = bk[i * CEMB + h * 32 + 16 + li];
    const float bv0 = bv[i * CEMB + h * 32 + li];
    const float bv1 = bv[i * CEMB + h * 32 + 16 + li];

    const unsigned short* wk0 = Wkt + ((size_t)(i * 256 + h * 32 + li)) * 256 + lg * 8;
    const unsigned short* wk1 = wk0 + 16 * 256;
    const unsigned short* wv0 = Wvt + ((size_t)(i * 256 + h * 32 + li)) * 256 + lg * 8;
    const unsigned short* wv1 = wv0 + 16 * 256;

    f32x16 kvacc = {};
    float ksa0 = 0.f, ksa1 = 0.f;

    {
        const int row0 = x0 * 64;
        const float* yb = y + ((size_t)(i * BB + b) * TT + row0) * CEMB;
        // issue first K-weight fragments BEFORE staging (fly under stage latency)
        short8 fk0 = *(const short8*)(wk0);
        short8 fk1 = *(const short8*)(wk1);
        #pragma unroll
        for (int j = 0; j < 8; ++j) {
            int idx = tid + j * 512;
            int r = idx >> 6, c4 = (idx & 63) << 2;
            int sw = ((((c4 >> 3) ^ (r & 7)) << 3) | (c4 & 7));
            float4 v4 = *(const float4*)&yb[(size_t)r * CEMB + c4];
            ushort4 p; p.x = f2bf(v4.x); p.y = f2bf(v4.y); p.z = f2bf(v4.z); p.w = f2bf(v4.w);
            *(ushort4*)&ytile[r][sw] = p;
        }
        __syncthreads();

        // ---------- K GEMM: acc[4][2], depth-1 pipelined weight loads ----------
        f32x4 acc[4][2];
        #pragma unroll
        for (int rt = 0; rt < 4; ++rt) { acc[rt][0] = (f32x4){}; acc[rt][1] = (f32x4){}; }
        #pragma unroll
        for (int ks = 0; ks < 8; ++ks) {
            short8 nk0, nk1;
            if (ks < 7) {
                nk0 = *(const short8*)(wk0 + (ks + 1) * 32);
                nk1 = *(const short8*)(wk1 + (ks + 1) * 32);
            }
            const int sw8 = (((4 * ks + lg) ^ lm) << 3);
            short8 a0 = *(const short8*)&ytile[li][sw8];
            short8 a1 = *(const short8*)&ytile[16 + li][sw8];
            short8 a2 = *(const short8*)&ytile[32 + li][sw8];
            short8 a3 = *(const short8*)&ytile[48 + li][sw8];
            acc[0][0] = __builtin_amdgcn_mfma_f32_16x16x32_bf16(a0, fk0, acc[0][0], 0, 0, 0);
            acc[0][1] = __builtin_amdgcn_mfma_f32_16x16x32_bf16(a0, fk1, acc[0][1], 0, 0, 0);
            acc[1][0] = __builtin_amdgcn_mfma_f32_16x16x32_bf16(a1, fk0, acc[1][0], 0, 0, 0);
            acc[1][1] = __builtin_amdgcn_mfma_f32_16x16x32_bf16(a1, fk1, acc[1][1], 0, 0, 0);
            acc[2][0] = __builtin_amdgcn_mfma_f32_16x16x32_bf16(a2, fk0, acc[2][0], 0, 0, 0);
            acc[2][1] = __builtin_amdgcn_mfma_f32_16x16x32_bf16(a2, fk1, acc[2][1], 0, 0, 0);
            acc[3][0] = __builtin_amdgcn_mfma_f32_16x16x32_bf16(a3, fk0, acc[3][0], 0, 0, 0);
            acc[3][1] = __builtin_amdgcn_mfma_f32_16x16x32_bf16(a3, fk1, acc[3][1], 0, 0, 0);
            fk0 = nk0; fk1 = nk1;
        }
        // issue first V-weight fragments (fly under softmax VALU work)
        short8 fv0 = *(const short8*)(wv0);
        short8 fv1 = *(const short8*)(wv1);
        // softmax(k) without max-sub -> kT into tr[wid]
        #pragma unroll
        for (int rt = 0; rt < 4; ++rt) {
            float kq0[4], kq1[4];
            #pragma unroll
            for (int reg = 0; reg < 4; ++reg) {
                float e0 = __expf(acc[rt][0][reg] + bk0);
                float e1 = __expf(acc[rt][1][reg] + bk1);
                float s = e0 + e1;
                s += __shfl_xor(s, 1, 16);
                s += __shfl_xor(s, 2, 16);
                s += __shfl_xor(s, 4, 16);
                s += __shfl_xor(s, 8, 16);
                float isv = 1.f / s;
                kq0[reg] = e0 * isv; kq1[reg] = e1 * isv;
                ksa0 += kq0[reg]; ksa1 += kq1[reg];
            }
            ushort4 p;
            p.x = f2bf(kq0[0]); p.y = f2bf(kq0[1]); p.z = f2bf(kq0[2]); p.w = f2bf(kq0[3]);
            *(ushort4*)&tr[wid][li][16 * rt + 4 * lg] = p;
            p.x = f2bf(kq1[0]); p.y = f2bf(kq1[1]); p.z = f2bf(kq1[2]); p.w = f2bf(kq1[3]);
            *(ushort4*)&tr[wid][16 + li][16 * rt + 4 * lg] = p;
        }
        // ---------- V GEMM: reuse acc, depth-1 pipelined weight loads ----------
        #pragma unroll
        for (int rt = 0; rt < 4; ++rt) { acc[rt][0] = (f32x4){}; acc[rt][1] = (f32x4){}; }
        #pragma unroll
        for (int ks = 0; ks < 8; ++ks) {
            short8 nv0, nv1;
            if (ks < 7) {
                nv0 = *(const short8*)(wv0 + (ks + 1) * 32);
                nv1 = *(const short8*)(wv1 + (ks + 1) * 32);
            }
            const int sw8 = (((4 * ks + lg) ^ lm) << 3);
            short8 a0 = *(const short8*)&ytile[li][sw8];
            short8 a1 = *(const short8*)&ytile[16 + li][sw8];
            short8 a2 = *(const short8*)&ytile[32 + li][sw8];
            short8 a3 = *(const short8*)&ytile[48 + li][sw8];
            acc[0][0] = __builtin_amdgcn_mfma_f32_16x16x32_bf16(a0, fv0, acc[0][0], 0, 0, 0);
            acc[0][1] = __builtin_amdgcn_mfma_f32_16x16x32_bf16(a0, fv1, acc[0][1], 0, 0, 0);
            acc[1][0] = __builtin_amdgcn_mfma_f32_16x16x32_bf16(a1, fv0, acc[1][0], 0, 0, 0);
            acc[1][1] = __builtin_amdgcn_mfma_f32_16x16x32_bf16(a1, fv1, acc[1][1], 0, 0, 0);
            acc[2][0] = __builtin_amdgcn_mfma_f32_16x16x32_bf16(a2, fv0, acc[2][0], 0, 0, 0);
            acc[2][1] = __builtin_amdgcn_mfma_f32_16x16x32_bf16(a2, fv1, acc[2][1], 0, 0, 0);
            acc[3][0] = __builtin_amdgcn_mfma_f32_16x16x32_bf16(a3, fv0, acc[3][0], 0, 0, 0);
            acc[3][1] = __builtin_amdgcn_mfma_f32_16x16x32_bf16(a3, fv1, acc[3][1], 0, 0, 0);
            fv0 = nv0; fv1 = nv1;
        }
        // read K fragments out before overwriting tr with V (wave-private buf)
        asm volatile("s_waitcnt lgkmcnt(0)" ::: "memory");
        short8 ka[4];
        #pragma unroll
        for (int ts = 0; ts < 4; ++ts)
            ka[ts] = *(const short8*)&tr[wid][l31][ts * 16 + hk * 8];
        asm volatile("s_waitcnt lgkmcnt(0)" ::: "memory");
        // vT into tr
        #pragma unroll
        for (int rt = 0; rt < 4; ++rt) {
            ushort4 p;
            p.x = f2bf(acc[rt][0][0] + bv0); p.y = f2bf(acc[rt][0][1] + bv0);
            p.z = f2bf(acc[rt][0][2] + bv0); p.w = f2bf(acc[rt][0][3] + bv0);
            *(ushort4*)&tr[wid][li][16 * rt + 4 * lg] = p;
            p.x = f2bf(acc[rt][1][0] + bv1); p.y = f2bf(acc[rt][1][1] + bv1);
            p.z = f2bf(acc[rt][1][2] + bv1); p.w = f2bf(acc[rt][1][3] + bv1);
            *(ushort4*)&tr[wid][16 + li][16 * rt + 4 * lg] = p;
        }
        asm volatile("s_waitcnt lgkmcnt(0)" ::: "memory");
        #pragma unroll
        for (int ts = 0; ts < 4; ++ts) {
            short8 vb = *(const short8*)&tr[wid][l31][ts * 16 + hk * 8];
            kvacc = __builtin_amdgcn_mfma_f32_32x32x16_bf16(ka[ts], vb, kvacc, 0, 0, 0);
        }
    }

    const size_t slot = (size_t)(i * BB + b) * SLOTS + x0;
    unsigned short* pb = part + slot * (NHEAD * 1056) + (size_t)h * 1056;
    #pragma unroll
    for (int reg = 0; reg < 16; ++reg) {
        int d = (reg & 3) + 8 * (reg >> 2) + 4 * hk;
        pb[d * 32 + l31] = f2bf(kvacc[reg]);
    }
    float s0 = ksa0, s1 = ksa1;
    s0 += __shfl_xor(s0, 16, 64); s0 += __shfl_xor(s0, 32, 64);
    s1 += __shfl_xor(s1, 16, 64); s1 += __shfl_xor(s1, 32, 64);
    if (lg == 0) { pb[1024 + li] = f2bf(s0); pb[1024 + 16 + li] = f2bf(s1); }
}

// ---- reduce bf16 partials (single stage, SLOTS summands, f32 accum) ----
__global__ __launch_bounds__(256) void reduceKV(const unsigned short* __restrict__ part,
    unsigned short* __restrict__ kvt, float* __restrict__ ksum)
{
    const int g = blockIdx.y, ech = blockIdx.x;
    const int ib = g >> 3, h = g & 7;
    const int tid = threadIdx.x;
    const int e0 = ech * 264;
    const int e1 = (e0 + 264 < 1056) ? e0 + 264 : 1056;
    for (int e = e0 + tid; e < e1; e += 256) {
        float s = 0.f;
        const unsigned short* p = part + ((size_t)ib * SLOTS * NHEAD + h) * 1056 + e;
        #pragma unroll 8
        for (int xx = 0; xx < SLOTS; ++xx) s += bf2f(p[(size_t)xx * NHEAD * 1056]);
        if (e < 1024) kvt[(size_t)g * 1024 + (e & 31) * 32 + (e >> 5)] = f2bf(s);
        else          ksum[(size_t)g * 32 + (e - 1024)] = s;
    }
}

// ---- pass B (R6 structure; max-drop softmax): 512 thr, wave w owns head w ----
__global__ __launch_bounds__(512, 4) void passB(const float* __restrict__ x,
    const float* __restrict__ bq, const float* __restrict__ bp,
    const unsigned short* __restrict__ Wqt, const unsigned short* __restrict__ Wpt,
    const unsigned short* __restrict__ kvt, const float* __restrict__ ksum,
    float* __restrict__ out)
{
    __shared__ unsigned short xa[64][256];     // XOR-swizzled; reused as out_pre
    __shared__ unsigned short ql[64][256];     // XOR-swizzled
    __shared__ float dl[2][64][8];

    const int b = blockIdx.y, x0 = blockIdx.x;
    const int row0 = x0 * 64;
    const int tid = threadIdx.x;
    const int wid = tid >> 6, lane = tid & 63, lg = lane >> 4, li = lane & 15;
    const int h = wid, lm = li & 7;

    const float* xb = x + ((size_t)b * TT + row0) * CEMB;
    #pragma unroll
    for (int j = 0; j < 8; ++j) {
        int idx = tid + j * 512;
        int r = idx >> 6, c4 = (idx & 63) << 2;
        int sw = ((((c4 >> 3) ^ (r & 7)) << 3) | (c4 & 7));
        float4 v4 = *(const float4*)&xb[(size_t)r * CEMB + c4];
        ushort4 p; p.x = f2bf(v4.x); p.y = f2bf(v4.y); p.z = f2bf(v4.z); p.w = f2bf(v4.w);
        *(ushort4*)&xa[r][sw] = p;
    }
    __syncthreads();

    // q projection: wave owns head h (2 col-tiles of 16)
    {
        f32x4 qa[4][2];
        #pragma unroll
        for (int rt = 0; rt < 4; ++rt) { qa[rt][0] = (f32x4){}; qa[rt][1] = (f32x4){}; }

        const unsigned short* wq0 = Wqt + ((size_t)(h * 32 + li)) * 256 + lg * 8;
        const unsigned short* wq1 = wq0 + 16 * 256;
        #pragma unroll 2
        for (int ks = 0; ks < 8; ++ks) {
            const int sw8 = (((4 * ks + lg) ^ lm) << 3);
            short8 a0 = *(const short8*)&xa[li][sw8];
            short8 a1 = *(const short8*)&xa[16 + li][sw8];
            short8 a2 = *(const short8*)&xa[32 + li][sw8];
            short8 a3 = *(const short8*)&xa[48 + li][sw8];
            short8 f0 = *(const short8*)(wq0 + ks * 32);
            short8 f1 = *(const short8*)(wq1 + ks * 32);
            qa[0][0] = __builtin_amdgcn_mfma_f32_16x16x32_bf16(a0, f0, qa[0][0], 0, 0, 0);
            qa[0][1] = __builtin_amdgcn_mfma_f32_16x16x32_bf16(a0, f1, qa[0][1], 0, 0, 0);
            qa[1][0] = __builtin_amdgcn_mfma_f32_16x16x32_bf16(a1, f0, qa[1][0], 0, 0, 0);
            qa[1][1] = __builtin_amdgcn_mfma_f32_16x16x32_bf16(a1, f1, qa[1][1], 0, 0, 0);
            qa[2][0] = __builtin_amdgcn_mfma_f32_16x16x32_bf16(a2, f0, qa[2][0], 0, 0, 0);
            qa[2][1] = __builtin_amdgcn_mfma_f32_16x16x32_bf16(a2, f1, qa[2][1], 0, 0, 0);
            qa[3][0] = __builtin_amdgcn_mfma_f32_16x16x32_bf16(a3, f0, qa[3][0], 0, 0, 0);
            qa[3][1] = __builtin_amdgcn_mfma_f32_16x16x32_bf16(a3, f1, qa[3][1], 0, 0, 0);
        }
        const float bq0 = bq[h * 32 + li];
        const float bq1 = bq[h * 32 + 16 + li];
        #pragma unroll
        for (int rt = 0; rt < 4; ++rt) {
            #pragma unroll
            for (int reg = 0; reg < 4; ++reg) {
                float e0 = __expf(qa[rt][0][reg] + bq0);
                float e1 = __expf(qa[rt][1][reg] + bq1);
                float s = e0 + e1;
                s += __shfl_xor(s, 1, 16);
                s += __shfl_xor(s, 2, 16);
                s += __shfl_xor(s, 4, 16);
                s += __shfl_xor(s, 8, 16);
                float isv = 1.f / s;
                int r = 16 * rt + 4 * lg + reg;
                int r7 = r & 7;
                int sw0 = (((4 * h + (li >> 3)) ^ r7) << 3) | lm;
                int sw1 = (((4 * h + 2 + (li >> 3)) ^ r7) << 3) | lm;
                ql[r][sw0] = f2bf(e0 * isv);
                ql[r][sw1] = f2bf(e1 * isv);
            }
        }
    }
    __syncthreads();

    // Dinv: 512 threads cover 64 rows x 8 heads
    {
        int r = tid >> 3, hh = tid & 7;
        const float* ks0 = ksum + ((size_t)(0 * BB + b) * 8 + hh) * 32;
        const float* ks1 = ksum + ((size_t)(1 * BB + b) * 8 + hh) * 32;
        float s0 = 0.f, s1 = 0.f;
        #pragma unroll
        for (int d8 = 0; d8 < 4; ++d8) {
            int cu = (((4 * hh + d8) ^ (r & 7)) << 3);
            #pragma unroll
            for (int dd = 0; dd < 8; ++dd) {
                float qv = bf2f(ql[r][cu + dd]);
                s0 += qv * ks0[d8 * 8 + dd];
                s1 += qv * ks1[d8 * 8 + dd];
            }
        }
        dl[0][r][hh] = 1.f / s0;
        dl[1][r][hh] = 1.f / s1;
    }
    __syncthreads();

    // attn for own head h: out_pre cols [h*32, h*32+32) over all 64 rows -> xa
    #pragma unroll
    for (int rt = 0; rt < 4; ++rt) {
        float of0[4], of1[4];
        #pragma unroll
        for (int reg = 0; reg < 4; ++reg) {
            int rk = (4 * lg + reg) & 7;
            int r = 16 * rt + 4 * lg + reg;
            int col0 = (((4 * h + (li >> 3)) ^ rk) << 3) | lm;
            int col1 = (((4 * h + 2 + (li >> 3)) ^ rk) << 3) | lm;
            of0[reg] = bf2f(ql[r][col0]);
            of1[reg] = bf2f(ql[r][col1]);
        }
        short8 af = *(const short8*)&ql[16 * rt + li][(((4 * h + lg) ^ lm) << 3)];
        #pragma unroll
        for (int ii = 0; ii < NIN; ++ii) {
            const unsigned short* kvb = kvt + ((size_t)((ii * BB + b) * 8 + h)) * 1024;
            short8 b0 = *(const short8*)(kvb + (size_t)li * 32 + lg * 8);
            short8 b1 = *(const short8*)(kvb + (size_t)(16 + li) * 32 + lg * 8);
            f32x4 z = {};
            f32x4 t0 = __builtin_amdgcn_mfma_f32_16x16x32_bf16(af, b0, z, 0, 0, 0);
            f32x4 t1 = __builtin_amdgcn_mfma_f32_16x16x32_bf16(af, b1, z, 0, 0, 0);
            #pragma unroll
            for (int reg = 0; reg < 4; ++reg) {
                float dv = dl[ii][16 * rt + 4 * lg + reg][h];
                of0[reg] += t0[reg] * dv;
                of1[reg] += t1[reg] * dv;
            }
        }
        #pragma unroll
        for (int reg = 0; reg < 4; ++reg) {
            int rk = (4 * lg + reg) & 7;
            int r = 16 * rt + 4 * lg + reg;
            int col0 = (((4 * h + (li >> 3)) ^ rk) << 3) | lm;
            int col1 = (((4 * h + 2 + (li >> 3)) ^ rk) << 3) | lm;
            xa[r][col0] = f2bf(of0[reg]);
            xa[r][col1] = f2bf(of1[reg]);
        }
    }
    __syncthreads();   // cross-wave: out-proj reads all cols of xa

    // out projection: wave owns col-tiles 2h, 2h+1
    {
        f32x4 of[4][2];
        #pragma unroll
        for (int rt = 0; rt < 4; ++rt) { of[rt][0] = (f32x4){}; of[rt][1] = (f32x4){}; }
        const unsigned short* wp0 = Wpt + ((size_t)(h * 32 + li)) * 256 + lg * 8;
        const unsigned short* wp1 = wp0 + 16 * 256;
        #pragma unroll 2
        for (int ks = 0; ks < 8; ++ks) {
            const int sw8 = (((4 * ks + lg) ^ lm) << 3);
            short8 a0 = *(const short8*)&xa[li][sw8];
            short8 a1 = *(const short8*)&xa[16 + li][sw8];
            short8 a2 = *(const short8*)&xa[32 + li][sw8];
            short8 a3 = *(const short8*)&xa[48 + li][sw8];
            short8 f0 = *(const short8*)(wp0 + ks * 32);
            short8 f1 = *(const short8*)(wp1 + ks * 32);
            of[0][0] = __builtin_amdgcn_mfma_f32_16x16x32_bf16(a0, f0, of[0][0], 0, 0, 0);
            of[0][1] = __builtin_amdgcn_mfma_f32_16x16x32_bf16(a0, f1, of[0][1], 0, 0, 0);
            of[1][0] = __builtin_amdgcn_mfma_f32_16x16x32_bf16(a1, f0, of[1][0], 0, 0, 0);
            of[1][1] = __builtin_amdgcn_mfma_f32_16x16x32_bf16(a1, f1, of[1][1], 0, 0, 0);
            of[2][0] = __builtin_amdgcn_mfma_f32_16x16x32_bf16(a2, f0, of[2][0], 0, 0, 0);
            of[2][1] = __builtin_amdgcn_mfma_f32_16x16x32_bf16(a2, f1, of[2][1], 0, 0, 0);
            of[3][0] = __builtin_amdgcn_mfma_f32_16x16x32_bf16(a3, f0, of[3][0], 0, 0, 0);
            of[3][1] = __builtin_amdgcn_mfma_f32_16x16x32_bf16(a3, f1, of[3][1], 0, 0, 0);
        }
        const float bp0 = bp[h * 32 + li];
        const float bp1 = bp[h * 32 + 16 + li];
        #pragma unroll
        for (int rt = 0; rt < 4; ++rt) {
            #pragma unroll
            for (int reg = 0; reg < 4; ++reg) {
                int r = 16 * rt + 4 * lg + reg;
                float* ob = out + ((size_t)b * TT + row0 + r) * CEMB + h * 32;
                ob[li]      = of[rt][0][reg] + bp0;
                ob[16 + li] = of[rt][1][reg] + bp1;
            }
        }
    }
}

extern "C" void kernel_launch(void* const* d_in, const int* in_sizes, int n_in,
                              void* d_out, int out_size, void* d_ws, size_t ws_size,
                              hipStream_t stream)
{
    const float* x  = (const float*)d_in[0];
    const float* y  = (const float*)d_in[1];
    const float* Wq = (const float*)d_in[2];
    const float* bq = (const float*)d_in[3];
    const float* Wk = (const float*)d_in[4];
    const float* bk = (const float*)d_in[5];
    const float* Wv = (const float*)d_in[6];
    const float* bv = (const float*)d_in[7];
    const float* Wp = (const float*)d_in[8];
    const float* bp = (const float*)d_in[9];
    float* out = (float*)d_out;

    unsigned short* wsb = (unsigned short*)d_ws;
    // layout: weights 768KB | part (bf16) 2*4*128*8*1056*2 = 17.3MB | kvt 128KB | ksum 8KB
    unsigned short* part = (unsigned short*)((char*)d_ws + 786432);
    const size_t partBytes = (size_t)NIN * BB * SLOTS * NHEAD * 1056 * 2;
    unsigned short* kvt = (unsigned short*)((char*)d_ws + 786432 + partBytes);
    float* ksum = (float*)((char*)d_ws + 786432 + partBytes + 131072);

    hipLaunchKernelGGL(prep_w, dim3(1536), dim3(256), 0, stream, Wq, Wk, Wv, Wp, wsb);
    hipLaunchKernelGGL(passA, dim3(SLOTS, BB, NIN), dim3(512), 0, stream,
                       y, bk, bv, wsb + 65536, wsb + 196608, part);
    hipLaunchKernelGGL(reduceKV, dim3(4, 64), dim3(256), 0, stream, part, kvt, ksum);
    hipLaunchKernelGGL(passB, dim3(128, BB), dim3(512), 0, stream,
                       x, bq, bp, wsb + 0, wsb + 327680, kvt, ksum, out);
}